// Round 1
// baseline (1037.610 us; speedup 1.0000x reference)
//
#include <hip/hip_runtime.h>
#include <math.h>

#define N_NODES 50000
#define N_EDGES 600000
#define D 128
#define EPS 1e-12f

// ---------------- K0: normalize question embedding (1 block, 128 threads) ---
__global__ void qnorm_kernel(const float* __restrict__ q, float* __restrict__ qn) {
    __shared__ float red[2];
    int t = threadIdx.x;
    float v = q[t];
    float ss = v * v;
    #pragma unroll
    for (int off = 32; off > 0; off >>= 1) ss += __shfl_down(ss, off);
    if ((t & 63) == 0) red[t >> 6] = ss;
    __syncthreads();
    float inv = 1.0f / fmaxf(sqrtf(red[0] + red[1]), EPS);
    qn[t] = v * inv;
}

// ---------------- K1: edge cosine sim, one wave (64 lanes) per edge ---------
__global__ void edge_sim_kernel(const float* __restrict__ ea,
                                const float* __restrict__ qn,
                                float* __restrict__ sim) {
    int gid  = blockIdx.x * blockDim.x + threadIdx.x;
    int wave = gid >> 6;
    int lane = threadIdx.x & 63;
    if (wave >= N_EDGES) return;
    const float2 v = ((const float2*)(ea + (size_t)wave * D))[lane];
    const float2 q = ((const float2*)qn)[lane];
    float dot = v.x * q.x + v.y * q.y;
    float ss  = v.x * v.x + v.y * v.y;
    #pragma unroll
    for (int off = 32; off > 0; off >>= 1) {
        dot += __shfl_down(dot, off);
        ss  += __shfl_down(ss, off);
    }
    if (lane == 0) sim[wave] = dot / fmaxf(sqrtf(ss), EPS);
}

// ---------------- K2: degree histogram + inverse -----------------------------
__global__ void deg_kernel(const int* __restrict__ dst, float* __restrict__ deg) {
    int e = blockIdx.x * blockDim.x + threadIdx.x;
    if (e < N_EDGES) atomicAdd(&deg[dst[e]], 1.0f);
}

__global__ void deg_inv_kernel(float* __restrict__ deg) {
    int n = blockIdx.x * blockDim.x + threadIdx.x;
    if (n < N_NODES) deg[n] = 1.0f / fmaxf(deg[n], 1.0f);
}

// ---------------- K3: scatter layer: xnew[dst] += x[src]*sim ----------------
// thread per (edge, channel); 128 consecutive threads share one edge so the
// gather of x[src] and the atomic scatter are both coalesced per edge row.
__global__ void scatter_kernel(const float* __restrict__ x,
                               const float* __restrict__ sim,
                               const int* __restrict__ src,
                               const int* __restrict__ dst,
                               float* __restrict__ xnew) {
    long long tid = (long long)blockIdx.x * blockDim.x + threadIdx.x;
    if (tid >= (long long)N_EDGES * D) return;
    int e = (int)(tid >> 7);
    int c = (int)(tid & (D - 1));
    float s = sim[e];          // same addr across the 128-thread group: broadcast
    int sn = src[e];
    int dn = dst[e];
    float val = x[(size_t)sn * D + c] * s;
    atomicAdd(&xnew[(size_t)dn * D + c], val);
}

// ---------------- K4: blend: out = 0.5*x + 0.5*xnew/deg ---------------------
__global__ void blend_kernel(const float* __restrict__ xin,
                             const float* __restrict__ xnew,
                             const float* __restrict__ deg_inv,
                             float* __restrict__ xout) {
    int tid = blockIdx.x * blockDim.x + threadIdx.x;
    const int nvec = N_NODES * D / 4;
    if (tid >= nvec) return;
    int n = tid / (D / 4);
    float4 a = ((const float4*)xin)[tid];
    float4 b = ((const float4*)xnew)[tid];
    float di = deg_inv[n];
    float4 o;
    o.x = 0.5f * a.x + 0.5f * b.x * di;
    o.y = 0.5f * a.y + 0.5f * b.y * di;
    o.z = 0.5f * a.z + 0.5f * b.z * di;
    o.w = 0.5f * a.w + 0.5f * b.w * di;
    ((float4*)xout)[tid] = o;
}

extern "C" void kernel_launch(void* const* d_in, const int* in_sizes, int n_in,
                              void* d_out, int out_size, void* d_ws, size_t ws_size,
                              hipStream_t stream) {
    const float* x  = (const float*)d_in[0];   // [N, D]
    const float* ea = (const float*)d_in[1];   // [E, D]
    const float* q  = (const float*)d_in[2];   // [D]
    const int*   ei = (const int*)d_in[3];     // [2, E]
    const int* src = ei;
    const int* dst = ei + N_EDGES;
    float* out = (float*)d_out;                // [N, D]

    // workspace layout (floats)
    float* ws   = (float*)d_ws;
    float* qn   = ws;                          // 128
    float* sim  = qn + 128;                    // N_EDGES
    float* deg  = sim + N_EDGES;               // N_NODES
    float* xnew = deg + N_NODES;               // N_NODES * D

    hipMemsetAsync(deg, 0, (size_t)N_NODES * sizeof(float), stream);
    hipMemsetAsync(xnew, 0, (size_t)N_NODES * D * sizeof(float), stream);

    qnorm_kernel<<<1, 128, 0, stream>>>(q, qn);

    {   // one wave per edge
        long long threads = (long long)N_EDGES * 64;
        int blocks = (int)((threads + 255) / 256);
        edge_sim_kernel<<<blocks, 256, 0, stream>>>(ea, qn, sim);
    }

    deg_kernel<<<(N_EDGES + 255) / 256, 256, 0, stream>>>(dst, deg);
    deg_inv_kernel<<<(N_NODES + 255) / 256, 256, 0, stream>>>(deg);

    const long long sc_threads = (long long)N_EDGES * D;
    const int sc_blocks = (int)((sc_threads + 255) / 256);
    const int bl_blocks = (N_NODES * D / 4 + 255) / 256;

    // ---- layer 1: x -> out
    scatter_kernel<<<sc_blocks, 256, 0, stream>>>(x, sim, src, dst, xnew);
    blend_kernel<<<bl_blocks, 256, 0, stream>>>(x, xnew, deg, out);

    // ---- layer 2: out -> out
    hipMemsetAsync(xnew, 0, (size_t)N_NODES * D * sizeof(float), stream);
    scatter_kernel<<<sc_blocks, 256, 0, stream>>>(out, sim, src, dst, xnew);
    blend_kernel<<<bl_blocks, 256, 0, stream>>>(out, xnew, deg, out);
}

// Round 2
// 635.582 us; speedup vs baseline: 1.6325x; 1.6325x over previous
//
#include <hip/hip_runtime.h>
#include <math.h>

#define N_NODES 50000
#define N_EDGES 600000
#define D 128
#define EPS 1e-12f

#define SCAN_B 256
#define N_SCAN_BLOCKS ((N_NODES + SCAN_B - 1) / SCAN_B)   // 196

// ---------------- K0: normalize question embedding (1 block, 128 threads) ---
__global__ void qnorm_kernel(const float* __restrict__ q, float* __restrict__ qn) {
    __shared__ float red[2];
    int t = threadIdx.x;
    float v = q[t];
    float ss = v * v;
    #pragma unroll
    for (int off = 32; off > 0; off >>= 1) ss += __shfl_down(ss, off);
    if ((t & 63) == 0) red[t >> 6] = ss;
    __syncthreads();
    float inv = 1.0f / fmaxf(sqrtf(red[0] + red[1]), EPS);
    qn[t] = v * inv;
}

// ---------------- K1: edge cosine sim, one wave (64 lanes) per edge ---------
__global__ void edge_sim_kernel(const float* __restrict__ ea,
                                const float* __restrict__ qn,
                                float* __restrict__ sim) {
    int gid  = blockIdx.x * blockDim.x + threadIdx.x;
    int wave = gid >> 6;
    int lane = threadIdx.x & 63;
    if (wave >= N_EDGES) return;
    const float2 v = ((const float2*)(ea + (size_t)wave * D))[lane];
    const float2 q = ((const float2*)qn)[lane];
    float dot = v.x * q.x + v.y * q.y;
    float ss  = v.x * v.x + v.y * v.y;
    #pragma unroll
    for (int off = 32; off > 0; off >>= 1) {
        dot += __shfl_down(dot, off);
        ss  += __shfl_down(ss, off);
    }
    if (lane == 0) sim[wave] = dot / fmaxf(sqrtf(ss), EPS);
}

// ---------------- K2: degree count ------------------------------------------
__global__ void count_kernel(const int* __restrict__ dst, int* __restrict__ cnt) {
    int e = blockIdx.x * blockDim.x + threadIdx.x;
    if (e < N_EDGES) atomicAdd(&cnt[dst[e]], 1);
}

__global__ void deg_inv_kernel(const int* __restrict__ cnt, float* __restrict__ deg_inv) {
    int n = blockIdx.x * blockDim.x + threadIdx.x;
    if (n < N_NODES) deg_inv[n] = 1.0f / fmaxf((float)cnt[n], 1.0f);
}

// ---------------- K3: 3-phase exclusive scan of cnt -> row_ptr ---------------
__global__ void block_sum_kernel(const int* __restrict__ cnt, int* __restrict__ bsum) {
    __shared__ int s[SCAN_B];
    int t = threadIdx.x;
    int i = blockIdx.x * SCAN_B + t;
    s[t] = (i < N_NODES) ? cnt[i] : 0;
    __syncthreads();
    for (int off = SCAN_B / 2; off > 0; off >>= 1) {
        if (t < off) s[t] += s[t + off];
        __syncthreads();
    }
    if (t == 0) bsum[blockIdx.x] = s[0];
}

__global__ void scan_bsums_kernel(int* __restrict__ bsum) {
    __shared__ int s[SCAN_B];
    int t = threadIdx.x;
    int v = (t < N_SCAN_BLOCKS) ? bsum[t] : 0;
    s[t] = v;
    __syncthreads();
    for (int off = 1; off < SCAN_B; off <<= 1) {
        int a = (t >= off) ? s[t - off] : 0;
        __syncthreads();
        s[t] += a;
        __syncthreads();
    }
    if (t < N_SCAN_BLOCKS) bsum[t] = s[t] - v;   // exclusive
}

__global__ void scan_final_kernel(const int* __restrict__ cnt,
                                  const int* __restrict__ bsum,
                                  int* __restrict__ row_ptr) {
    __shared__ int s[SCAN_B];
    int t = threadIdx.x;
    int i = blockIdx.x * SCAN_B + t;
    int v = (i < N_NODES) ? cnt[i] : 0;
    s[t] = v;
    __syncthreads();
    for (int off = 1; off < SCAN_B; off <<= 1) {
        int a = (t >= off) ? s[t - off] : 0;
        __syncthreads();
        s[t] += a;
        __syncthreads();
    }
    if (i < N_NODES) row_ptr[i] = s[t] - v + bsum[blockIdx.x];
    if (i == N_NODES - 1) row_ptr[N_NODES] = N_EDGES;
}

// ---------------- K4: fill CSR (src id + sim per incoming edge) -------------
__global__ void fill_kernel(const int* __restrict__ src, const int* __restrict__ dst,
                            const float* __restrict__ sim,
                            int* __restrict__ cursor,
                            int* __restrict__ csr_src, float* __restrict__ csr_sim) {
    int e = blockIdx.x * blockDim.x + threadIdx.x;
    if (e >= N_EDGES) return;
    int d = dst[e];
    int idx = atomicAdd(&cursor[d], 1);
    csr_src[idx] = src[e];
    csr_sim[idx] = sim[e];
}

// ---------------- K5: fused gather-aggregate + mean + residual blend --------
// one wave per node; lane holds float2 (64*2 = 128 = D). No atomics: each
// output row is written exactly once.
__global__ void agg_kernel(const float* __restrict__ xin,
                           const int* __restrict__ row_ptr,
                           const int* __restrict__ csr_src,
                           const float* __restrict__ csr_sim,
                           const float* __restrict__ deg_inv,
                           float* __restrict__ xout) {
    int gid  = blockIdx.x * blockDim.x + threadIdx.x;
    int node = gid >> 6;
    int lane = threadIdx.x & 63;
    if (node >= N_NODES) return;
    int beg = row_ptr[node];
    int end = row_ptr[node + 1];
    float2 acc = make_float2(0.0f, 0.0f);
    int j = beg;
    // 2-wide manual unroll: two independent gathers in flight per iter
    for (; j + 1 < end; j += 2) {
        int   s0 = csr_src[j],     s1 = csr_src[j + 1];
        float w0 = csr_sim[j],     w1 = csr_sim[j + 1];
        float2 v0 = ((const float2*)(xin + (size_t)s0 * D))[lane];
        float2 v1 = ((const float2*)(xin + (size_t)s1 * D))[lane];
        acc.x += v0.x * w0 + v1.x * w1;
        acc.y += v0.y * w0 + v1.y * w1;
    }
    if (j < end) {
        int   s0 = csr_src[j];
        float w0 = csr_sim[j];
        float2 v0 = ((const float2*)(xin + (size_t)s0 * D))[lane];
        acc.x += v0.x * w0;
        acc.y += v0.y * w0;
    }
    float di = deg_inv[node];
    float2 a = ((const float2*)(xin + (size_t)node * D))[lane];
    float2 o;
    o.x = 0.5f * a.x + 0.5f * acc.x * di;
    o.y = 0.5f * a.y + 0.5f * acc.y * di;
    ((float2*)(xout + (size_t)node * D))[lane] = o;
}

extern "C" void kernel_launch(void* const* d_in, const int* in_sizes, int n_in,
                              void* d_out, int out_size, void* d_ws, size_t ws_size,
                              hipStream_t stream) {
    const float* x  = (const float*)d_in[0];   // [N, D]
    const float* ea = (const float*)d_in[1];   // [E, D]
    const float* q  = (const float*)d_in[2];   // [D]
    const int*   ei = (const int*)d_in[3];     // [2, E]
    const int* src = ei;
    const int* dst = ei + N_EDGES;
    float* out = (float*)d_out;                // [N, D]

    // ---- workspace layout (x1 first for 16B alignment) ----
    float* x1       = (float*)d_ws;                       // N*D floats
    float* sim      = x1 + (size_t)N_NODES * D;           // E
    float* csr_sim  = sim + N_EDGES;                      // E
    float* deg_inv  = csr_sim + N_EDGES;                  // N
    float* qn       = deg_inv + N_NODES;                  // 128
    int*   cnt      = (int*)(qn + 128);                   // N
    int*   row_ptr  = cnt + N_NODES;                      // N+1
    int*   cursor   = row_ptr + N_NODES + 1;              // N
    int*   bsum     = cursor + N_NODES;                   // 256
    int*   csr_src  = bsum + 256;                         // E

    hipMemsetAsync(cnt, 0, (size_t)N_NODES * sizeof(int), stream);

    qnorm_kernel<<<1, 128, 0, stream>>>(q, qn);

    {   // one wave per edge
        long long threads = (long long)N_EDGES * 64;
        int blocks = (int)((threads + 255) / 256);
        edge_sim_kernel<<<blocks, 256, 0, stream>>>(ea, qn, sim);
    }

    const int eb = (N_EDGES + 255) / 256;
    count_kernel<<<eb, 256, 0, stream>>>(dst, cnt);
    deg_inv_kernel<<<(N_NODES + 255) / 256, 256, 0, stream>>>(cnt, deg_inv);

    block_sum_kernel<<<N_SCAN_BLOCKS, SCAN_B, 0, stream>>>(cnt, bsum);
    scan_bsums_kernel<<<1, SCAN_B, 0, stream>>>(bsum);
    scan_final_kernel<<<N_SCAN_BLOCKS, SCAN_B, 0, stream>>>(cnt, bsum, row_ptr);

    hipMemcpyAsync(cursor, row_ptr, (size_t)N_NODES * sizeof(int),
                   hipMemcpyDeviceToDevice, stream);
    fill_kernel<<<eb, 256, 0, stream>>>(src, dst, sim, cursor, csr_src, csr_sim);

    const int agg_blocks = (int)(((long long)N_NODES * 64 + 255) / 256);
    // layer 1: x -> x1 ; layer 2: x1 -> out (no in-place hazard)
    agg_kernel<<<agg_blocks, 256, 0, stream>>>(x,  row_ptr, csr_src, csr_sim, deg_inv, x1);
    agg_kernel<<<agg_blocks, 256, 0, stream>>>(x1, row_ptr, csr_src, csr_sim, deg_inv, out);
}

// Round 3
// 563.852 us; speedup vs baseline: 1.8402x; 1.1272x over previous
//
#include <hip/hip_runtime.h>
#include <math.h>

#define N_NODES 50000
#define N_EDGES 600000
#define D 128
#define EPS 1e-12f

#define SCAN_B 256
#define N_SCAN_BLOCKS ((N_NODES + SCAN_B - 1) / SCAN_B)   // 196

// ---------------- K0: normalize question embedding (1 block, 128 threads) ---
__global__ void qnorm_kernel(const float* __restrict__ q, float* __restrict__ qn) {
    __shared__ float red[2];
    int t = threadIdx.x;
    float v = q[t];
    float ss = v * v;
    #pragma unroll
    for (int off = 32; off > 0; off >>= 1) ss += __shfl_down(ss, off);
    if ((t & 63) == 0) red[t >> 6] = ss;
    __syncthreads();
    float inv = 1.0f / fmaxf(sqrtf(red[0] + red[1]), EPS);
    qn[t] = v * inv;
}

// ---------------- K1: edge cosine sim + degree count ------------------------
// two edges per wave: lanes 0-31 edge 2w, lanes 32-63 edge 2w+1, float4/lane.
__global__ void edge_sim_kernel(const float* __restrict__ ea,
                                const float* __restrict__ qn,
                                const int* __restrict__ dst,
                                float* __restrict__ sim,
                                int* __restrict__ cnt) {
    int gid  = blockIdx.x * blockDim.x + threadIdx.x;
    int wave = gid >> 6;
    if (wave >= N_EDGES / 2) return;
    int lane = threadIdx.x & 63;
    int half = lane >> 5;
    int l32  = lane & 31;
    int e    = 2 * wave + half;

    float4 v = ((const float4*)(ea + (size_t)e * D))[l32];
    float4 q = ((const float4*)qn)[l32];
    float dot = v.x * q.x + v.y * q.y + v.z * q.z + v.w * q.w;
    float ss  = v.x * v.x + v.y * v.y + v.z * v.z + v.w * v.w;
    // reduce within each 32-lane half (xor offsets < 32 never cross halves)
    #pragma unroll
    for (int off = 16; off > 0; off >>= 1) {
        dot += __shfl_xor(dot, off);
        ss  += __shfl_xor(ss, off);
    }
    if (l32 == 0) {
        sim[e] = dot / fmaxf(sqrtf(ss), EPS);
        atomicAdd(&cnt[dst[e]], 1);
    }
}

// ---------------- K2: 3-phase exclusive scan of cnt -> row_ptr ---------------
__global__ void block_sum_kernel(const int* __restrict__ cnt, int* __restrict__ bsum) {
    __shared__ int s[SCAN_B];
    int t = threadIdx.x;
    int i = blockIdx.x * SCAN_B + t;
    s[t] = (i < N_NODES) ? cnt[i] : 0;
    __syncthreads();
    for (int off = SCAN_B / 2; off > 0; off >>= 1) {
        if (t < off) s[t] += s[t + off];
        __syncthreads();
    }
    if (t == 0) bsum[blockIdx.x] = s[0];
}

__global__ void scan_bsums_kernel(int* __restrict__ bsum) {
    __shared__ int s[SCAN_B];
    int t = threadIdx.x;
    int v = (t < N_SCAN_BLOCKS) ? bsum[t] : 0;
    s[t] = v;
    __syncthreads();
    for (int off = 1; off < SCAN_B; off <<= 1) {
        int a = (t >= off) ? s[t - off] : 0;
        __syncthreads();
        s[t] += a;
        __syncthreads();
    }
    if (t < N_SCAN_BLOCKS) bsum[t] = s[t] - v;   // exclusive
}

// also emits deg_inv and cursor (saves two dispatches)
__global__ void scan_final_kernel(const int* __restrict__ cnt,
                                  const int* __restrict__ bsum,
                                  int* __restrict__ row_ptr,
                                  int* __restrict__ cursor,
                                  float* __restrict__ deg_inv) {
    __shared__ int s[SCAN_B];
    int t = threadIdx.x;
    int i = blockIdx.x * SCAN_B + t;
    int v = (i < N_NODES) ? cnt[i] : 0;
    s[t] = v;
    __syncthreads();
    for (int off = 1; off < SCAN_B; off <<= 1) {
        int a = (t >= off) ? s[t - off] : 0;
        __syncthreads();
        s[t] += a;
        __syncthreads();
    }
    if (i < N_NODES) {
        int rp = s[t] - v + bsum[blockIdx.x];
        row_ptr[i] = rp;
        cursor[i]  = rp;
        deg_inv[i] = 1.0f / fmaxf((float)v, 1.0f);
    }
    if (i == N_NODES - 1) row_ptr[N_NODES] = N_EDGES;
}

// ---------------- K3: fill CSR (src id + sim per incoming edge) -------------
__global__ void fill_kernel(const int* __restrict__ src, const int* __restrict__ dst,
                            const float* __restrict__ sim,
                            int* __restrict__ cursor,
                            int* __restrict__ csr_src, float* __restrict__ csr_sim) {
    int e = blockIdx.x * blockDim.x + threadIdx.x;
    if (e >= N_EDGES) return;
    int d = dst[e];
    int idx = atomicAdd(&cursor[d], 1);
    csr_src[idx] = src[e];
    csr_sim[idx] = sim[e];
}

// ---------------- K4: fused gather-aggregate + mean + residual blend --------
// one wave per node. CSR entries preloaded into lane registers (one coalesced
// load pair), broadcast per-edge via shfl. Gather rows as float4 across 32
// lanes; the two wave halves process even/odd edges concurrently.
__global__ void agg_kernel(const float* __restrict__ xin,
                           const int* __restrict__ row_ptr,
                           const int* __restrict__ csr_src,
                           const float* __restrict__ csr_sim,
                           const float* __restrict__ deg_inv,
                           float* __restrict__ xout) {
    int gid  = blockIdx.x * blockDim.x + threadIdx.x;
    int node = gid >> 6;
    if (node >= N_NODES) return;
    int lane = threadIdx.x & 63;
    int half = lane >> 5;
    int l32  = lane & 31;

    int beg = row_ptr[node];
    int end = row_ptr[node + 1];
    int n   = end - beg;

    // preload up to 64 (src, sim) pairs into registers — coalesced
    int   sl = 0; float wl = 0.0f;
    if (lane < n) { sl = csr_src[beg + lane]; wl = csr_sim[beg + lane]; }

    float4 acc = make_float4(0.0f, 0.0f, 0.0f, 0.0f);
    int nn = (n < 64) ? n : 64;
    // halves interleave: half 0 takes even edges, half 1 odd
    #pragma unroll 2
    for (int j = half; j < nn; j += 2) {
        int   s = __shfl(sl, j);
        float w = __shfl(wl, j);
        float4 v = ((const float4*)(xin + (size_t)s * D))[l32];
        acc.x += v.x * w; acc.y += v.y * w; acc.z += v.z * w; acc.w += v.w * w;
    }
    // safety: degree > 64 (Poisson(12) — effectively never, but correct)
    for (int j = 64 + half; j < n; j += 2) {
        int   s = csr_src[beg + j];
        float w = csr_sim[beg + j];
        float4 v = ((const float4*)(xin + (size_t)s * D))[l32];
        acc.x += v.x * w; acc.y += v.y * w; acc.z += v.z * w; acc.w += v.w * w;
    }
    // combine the two halves
    acc.x += __shfl_xor(acc.x, 32);
    acc.y += __shfl_xor(acc.y, 32);
    acc.z += __shfl_xor(acc.z, 32);
    acc.w += __shfl_xor(acc.w, 32);

    if (half == 0) {
        float di = deg_inv[node];
        float4 a = ((const float4*)(xin + (size_t)node * D))[l32];
        float4 o;
        o.x = 0.5f * a.x + 0.5f * acc.x * di;
        o.y = 0.5f * a.y + 0.5f * acc.y * di;
        o.z = 0.5f * a.z + 0.5f * acc.z * di;
        o.w = 0.5f * a.w + 0.5f * acc.w * di;
        ((float4*)(xout + (size_t)node * D))[l32] = o;
    }
}

extern "C" void kernel_launch(void* const* d_in, const int* in_sizes, int n_in,
                              void* d_out, int out_size, void* d_ws, size_t ws_size,
                              hipStream_t stream) {
    const float* x  = (const float*)d_in[0];   // [N, D]
    const float* ea = (const float*)d_in[1];   // [E, D]
    const float* q  = (const float*)d_in[2];   // [D]
    const int*   ei = (const int*)d_in[3];     // [2, E]
    const int* src = ei;
    const int* dst = ei + N_EDGES;
    float* out = (float*)d_out;                // [N, D]

    // ---- workspace layout (x1 first for 16B alignment) ----
    float* x1       = (float*)d_ws;                       // N*D floats
    float* sim      = x1 + (size_t)N_NODES * D;           // E
    float* csr_sim  = sim + N_EDGES;                      // E
    float* deg_inv  = csr_sim + N_EDGES;                  // N
    float* qn       = deg_inv + N_NODES;                  // 128
    int*   cnt      = (int*)(qn + 128);                   // N
    int*   row_ptr  = cnt + N_NODES;                      // N+1
    int*   cursor   = row_ptr + N_NODES + 1;              // N
    int*   bsum     = cursor + N_NODES;                   // 256
    int*   csr_src  = bsum + 256;                         // E

    hipMemsetAsync(cnt, 0, (size_t)N_NODES * sizeof(int), stream);

    qnorm_kernel<<<1, 128, 0, stream>>>(q, qn);

    {   // one wave per 2 edges
        long long threads = (long long)(N_EDGES / 2) * 64;
        int blocks = (int)((threads + 255) / 256);
        edge_sim_kernel<<<blocks, 256, 0, stream>>>(ea, qn, dst, sim, cnt);
    }

    block_sum_kernel<<<N_SCAN_BLOCKS, SCAN_B, 0, stream>>>(cnt, bsum);
    scan_bsums_kernel<<<1, SCAN_B, 0, stream>>>(bsum);
    scan_final_kernel<<<N_SCAN_BLOCKS, SCAN_B, 0, stream>>>(cnt, bsum, row_ptr, cursor, deg_inv);

    fill_kernel<<<(N_EDGES + 255) / 256, 256, 0, stream>>>(src, dst, sim, cursor, csr_src, csr_sim);

    const int agg_blocks = (int)(((long long)N_NODES * 64 + 255) / 256);
    // layer 1: x -> x1 ; layer 2: x1 -> out (no in-place hazard)
    agg_kernel<<<agg_blocks, 256, 0, stream>>>(x,  row_ptr, csr_src, csr_sim, deg_inv, x1);
    agg_kernel<<<agg_blocks, 256, 0, stream>>>(x1, row_ptr, csr_src, csr_sim, deg_inv, out);
}